// Round 5
// baseline (326.707 us; speedup 1.0000x reference)
//
#include <hip/hip_runtime.h>
#include <hip/hip_bf16.h>

typedef short bf16x8 __attribute__((ext_vector_type(8)));
typedef short bf16x4 __attribute__((ext_vector_type(4)));
typedef float f32x4 __attribute__((ext_vector_type(4)));

#define ALPHA_Q 0.1803368801111204f   // 0.125 * log2(e): softmax scale + exp2 base folded into q

static __device__ __forceinline__ unsigned short f2bf(float f) {
  unsigned u = __float_as_uint(f);
  u += 0x7fffu + ((u >> 16) & 1u);           // RNE
  return (unsigned short)(u >> 16);
}
static __device__ __forceinline__ float bf2f(unsigned short h) {
  return __uint_as_float((unsigned)h << 16);
}

// ---------------------------------------------------------------------------
// fp32 -> bf16 convert (weights)
// ---------------------------------------------------------------------------
__global__ __launch_bounds__(256) void cvt_w(const float* __restrict__ x,
                                             unsigned short* __restrict__ y, int n4) {
  int i = blockIdx.x * 256 + threadIdx.x;
  if (i >= n4) return;
  float4 v = ((const float4*)x)[i];
  uint2 o;
  o.x = (unsigned)f2bf(v.x) | ((unsigned)f2bf(v.y) << 16);
  o.y = (unsigned)f2bf(v.z) | ((unsigned)f2bf(v.w) << 16);
  ((uint2*)y)[i] = o;
}

// pe [513][64] fp32 ->
//   pe_b [608][64]  : pe rows 0..512, zero-padded above (bias-GEMM B, normal)
//   peT1 [64][640]  : peT1[d][y] = pe[y+1][d] (y<512), else 0 (out-band A, normal)
//   peB  [64][128]  : peB[d][u]  = pe[max(u-63,0)][d]         (out-band A, boundary)
//   peBb [128][64]  : peBb[v][d] = pe[max(v-63,0)][d]         (bias-GEMM B, boundary)
__global__ __launch_bounds__(256) void pe_prep(const float* __restrict__ pe,
                                               unsigned short* __restrict__ pe_b,
                                               unsigned short* __restrict__ peT1,
                                               unsigned short* __restrict__ peB,
                                               unsigned short* __restrict__ peBb) {
  int i = blockIdx.x * 256 + threadIdx.x;
  if (i < 608 * 64) {
    int r = i >> 6, d = i & 63;
    pe_b[i] = (r <= 512) ? f2bf(pe[r * 64 + d]) : (unsigned short)0;
  }
  if (i < 64 * 640) {
    int d = i / 640, y = i % 640;
    peT1[i] = (y < 512) ? f2bf(pe[(y + 1) * 64 + d]) : (unsigned short)0;
  }
  if (i < 64 * 128) {
    int d = i >> 7, u = i & 127;
    peB[i] = f2bf(pe[(u > 63 ? u - 63 : 0) * 64 + d]);
  }
  if (i < 128 * 64) {
    int v = i >> 6, d = i & 63;
    peBb[i] = f2bf(pe[(v > 63 ? v - 63 : 0) * 64 + d]);
  }
}

// ---------------------------------------------------------------------------
// NT GEMM via MFMA: Y[m][n] = (sum_k A[m][k]*W[n][k] + bias[n]) * scale
// M=8192 N=512 K=512. BM=128 BN=64 BK=64, 512 thr (8 waves, 16 rows each),
// double-buffered staging, 1 barrier/iter. z selects one of up to 3 problems.
// ---------------------------------------------------------------------------
struct GemmArgs {
  const void* X[3];
  const unsigned short* W[3];
  const float* bias[3];
  float scale[3];
  unsigned short* Yb[3];
  float* Yf;
};

template<int AFP32>
__global__ __launch_bounds__(512) void gemm_nt(GemmArgs ga) {
  __shared__ __align__(16) unsigned short asb[2][128][72];
  __shared__ __align__(16) unsigned short bsb[2][64][72];
  const int z = blockIdx.z;
  const void* Xv = ga.X[z];
  const unsigned short* W = ga.W[z];
  const int t = threadIdx.x;
  const int wid = t >> 6, lane = t & 63;
  const int l15 = lane & 15, l4 = lane >> 4;
  const int n0 = blockIdx.x << 6, m0 = blockIdx.y << 7;
  const int wr0 = wid << 4;

  f32x4 acc[4];
#pragma unroll
  for (int j = 0; j < 4; ++j) acc[j] = (f32x4){0.f, 0.f, 0.f, 0.f};

  auto stage = [&](int k0, int buf) {
    if (AFP32) {
      const float* X = (const float*)Xv;
#pragma unroll
      for (int i = 0; i < 4; ++i) {
        int idx = t + (i << 9);
        int row = idx >> 4, c4 = (idx & 15) << 2;
        float4 v = *(const float4*)(X + (size_t)(m0 + row) * 512 + k0 + c4);
        uint2 o;
        o.x = (unsigned)f2bf(v.x) | ((unsigned)f2bf(v.y) << 16);
        o.y = (unsigned)f2bf(v.z) | ((unsigned)f2bf(v.w) << 16);
        *(uint2*)&asb[buf][row][c4] = o;
      }
    } else {
      const unsigned short* X = (const unsigned short*)Xv;
#pragma unroll
      for (int i = 0; i < 2; ++i) {
        int idx = t + (i << 9);
        int row = idx >> 3, g8 = (idx & 7) << 3;
        *(bf16x8*)&asb[buf][row][g8] = *(const bf16x8*)(X + (size_t)(m0 + row) * 512 + k0 + g8);
      }
    }
    int row = t >> 3, g8 = (t & 7) << 3;
    *(bf16x8*)&bsb[buf][row][g8] = *(const bf16x8*)(W + (size_t)(n0 + row) * 512 + k0 + g8);
  };

  stage(0, 0);
  __syncthreads();
  for (int it = 0; it < 8; ++it) {
    const int buf = it & 1;
    if (it < 7) stage((it + 1) << 6, buf ^ 1);
#pragma unroll
    for (int ks = 0; ks < 2; ++ks) {
      bf16x8 af = *(const bf16x8*)&asb[buf][wr0 + l15][(ks << 5) + (l4 << 3)];
#pragma unroll
      for (int j = 0; j < 4; ++j) {
        bf16x8 bw = *(const bf16x8*)&bsb[buf][(j << 4) + l15][(ks << 5) + (l4 << 3)];
        acc[j] = __builtin_amdgcn_mfma_f32_16x16x32_bf16(af, bw, acc[j], 0, 0, 0);
      }
    }
    __syncthreads();
  }

  const float* bias = ga.bias[z];
  const float scale = ga.scale[z];
#pragma unroll
  for (int j = 0; j < 4; ++j) {
    const int n = n0 + (j << 4) + l15;
    const float bn = bias[n];
#pragma unroll
    for (int r = 0; r < 4; ++r) {
      const int m = m0 + wr0 + (l4 << 2) + r;
      float v = (acc[j][r] + bn) * scale;
      if (AFP32) ga.Yb[z][(size_t)m * 512 + n] = f2bf(v);
      else       ga.Yf[(size_t)m * 512 + n] = v;
    }
  }
}

// ---------------------------------------------------------------------------
// Fused causal attention, 128 q-rows per block as two private 64-row halves.
// 8 waves (512 thr): waves 0-3 = half lo, 4-7 = half hi; 16 rows per wave.
// Per chunk (64 s): QK^T + transposed bias-GEMM (masked b64 band writes) +
// P-phase + PV + transposed wave-private out-band GEMM. 2 barriers/chunk
// (K/V staging lifecycle only). All of pb/band are wave-private.
// ---------------------------------------------------------------------------
__global__ __launch_bounds__(512, 4) void attn_mfma(
    const unsigned short* __restrict__ qb,
    const unsigned short* __restrict__ kb,
    const unsigned short* __restrict__ vb,
    const unsigned short* __restrict__ pe_b,
    const unsigned short* __restrict__ peT1,
    const unsigned short* __restrict__ peB,
    const unsigned short* __restrict__ peBb,
    const float* __restrict__ pe,
    unsigned short* __restrict__ Oa) {
  const int bid = blockIdx.x;
  const int bh = bid & 63;               // same bh -> same XCD (bid%8 preserved)
  const int b = bh >> 3, h = bh & 7;
  const int g = bid >> 6;
  const int tile = (g < 4) ? (7 - g) : (g - 4);  // pair sums = 18 chunks/CU
  const int l0 = tile << 7;
  const int nch = (tile << 1) + 2;

  const int t = threadIdx.x;
  const int wid = t >> 6, lane = t & 63;
  const int l15 = lane & 15, l4 = lane >> 4;
  const int half = wid >> 2;
  const int wq = wid & 3;
  const int wr0p = wq << 4;              // wave row offset within half
  const int l0H = l0 + (half << 6);
  const int t64 = (tile << 1) + half;    // this half's 64-granular tile index

  __shared__ __align__(16) unsigned short ksb[64][72];
  __shared__ __align__(16) unsigned short vtb[64][72];
  __shared__ __align__(16) unsigned short pb2[2][64][72];
  __shared__ __align__(16) unsigned short band2[2][64][136];
  __shared__ float qa_lds[128];

  unsigned short (*pb)[72] = pb2[half];
  unsigned short (*band)[136] = band2[half];

  // zero band once; complement of each row's chunk-invariant window stays 0
  {
    unsigned int* z = (unsigned int*)&band2[0][0][0];
#pragma unroll
    for (int i = 0; i < 17; ++i) z[t + (i << 9)] = 0u;
  }

  // q fragment (pre-scaled by ALPHA_Q): rows l0 + wid*16 + l15
  bf16x8 aq[2];
  {
    const unsigned short* qp_ = qb + (size_t)(b * 1024 + l0 + (wid << 4) + l15) * 512 + h * 64 + (l4 << 3);
    aq[0] = *(const bf16x8*)qp_;
    aq[1] = *(const bf16x8*)(qp_ + 32);
  }
  // qa0 = q . pe[0] (for fully-clipped chunks)
  {
    float part = 0.f;
#pragma unroll
    for (int ks = 0; ks < 2; ++ks)
#pragma unroll
      for (int i = 0; i < 8; ++i)
        part += bf2f((unsigned short)aq[ks][i]) * pe[(ks << 5) + (l4 << 3) + i];
    part += __shfl_xor(part, 16, 64);
    part += __shfl_xor(part, 32, 64);
    if (lane < 16) qa_lds[(wid << 4) + l15] = part;
  }

  f32x4 ov[4], ow[4];
#pragma unroll
  for (int f = 0; f < 4; ++f) {
    ov[f] = (f32x4){0.f, 0.f, 0.f, 0.f};
    ow[f] = (f32x4){0.f, 0.f, 0.f, 0.f};
  }
  float denr[4] = {0.f, 0.f, 0.f, 0.f};
  float pr0r[4] = {0.f, 0.f, 0.f, 0.f};

  const int srow = t >> 3, sg = t & 7;
  bf16x8 kreg, vreg;
  auto LOADKV = [&](int cc) {
    const size_t ga = (size_t)(b * 1024 + (cc << 6) + srow) * 512 + h * 64 + (sg << 3);
    kreg = *(const bf16x8*)(kb + ga);
    vreg = *(const bf16x8*)(vb + ga);
  };
  auto WRITEKV = [&]() {
    *(bf16x8*)&ksb[srow][sg << 3] = kreg;
    const int col = (((srow >> 3) ^ sg) << 3) + (srow & 7);  // bank-uniform transpose
#pragma unroll
    for (int j = 0; j < 8; ++j)
      vtb[(sg << 3) + j][col] = (unsigned short)vreg[j];
  };

  LOADKV(0);
  WRITEKV();
  __syncthreads();

  for (int c = 0; c < nch; ++c) {
    const int s0 = c << 6;
    const bool active = (c <= t64);
    const bool clipped = (c <= t64 - 9);
    const bool bnd = (c == t64 - 8);
    if (c + 1 < nch) LOADKV(c + 1);          // T14: issue early, write after barrier

    if (active) {
      // ---- issue bias B-frag loads (L2), then QK on LDS while they fly ----
      bf16x8 bp0[5], bp1[5];
      const int f8lo = 3 - wq;
      const unsigned short* bsrcB = nullptr;
      if (!clipped) {
        bsrcB = bnd ? peBb : (pe_b + (size_t)(s0 - l0H + 449) * 64);
#pragma unroll
        for (int i = 0; i < 5; ++i) {
          const unsigned short* p_ = bsrcB + (size_t)(((f8lo + i) << 4) + l15) * 64 + (l4 << 3);
          bp0[i] = *(const bf16x8*)p_;
          bp1[i] = *(const bf16x8*)(p_ + 32);
        }
      }

      __builtin_amdgcn_s_setprio(1);
      // ---- QK^T ----
      f32x4 sc[4];
#pragma unroll
      for (int f = 0; f < 4; ++f) sc[f] = (f32x4){0.f, 0.f, 0.f, 0.f};
#pragma unroll
      for (int ks = 0; ks < 2; ++ks)
#pragma unroll
        for (int f = 0; f < 4; ++f) {
          bf16x8 bk = *(const bf16x8*)&ksb[(f << 4) + l15][(ks << 5) + (l4 << 3)];
          sc[f] = __builtin_amdgcn_mfma_f32_16x16x32_bf16(aq[ks], bk, sc[f], 0, 0, 0);
        }

      // ---- transposed bias GEMM: D[v][row] = pe[v+voff] . q[row] ----
      if (!clipped) {
        f32x4 macc[5];
#pragma unroll
        for (int i = 0; i < 5; ++i) macc[i] = (f32x4){0.f, 0.f, 0.f, 0.f};
#pragma unroll
        for (int i = 0; i < 5; ++i) {
          macc[i] = __builtin_amdgcn_mfma_f32_16x16x32_bf16(bp0[i], aq[0], macc[i], 0, 0, 0);
          macc[i] = __builtin_amdgcn_mfma_f32_16x16x32_bf16(bp1[i], aq[1], macc[i], 0, 0, 0);
        }
        __builtin_amdgcn_s_setprio(0);
        // masked writes: only the row's valid window [63-row', 126-row']
        const int rowp = wr0p + l15;
        const int Aw = 63 - rowp, Bw = 126 - rowp;
#pragma unroll
        for (int i = 0; i < 5; ++i) {
          const int v0 = ((f8lo + i) << 4) + (l4 << 2);
          if (v0 >= Aw && v0 + 3 <= Bw) {
            bf16x4 pk;
#pragma unroll
            for (int r = 0; r < 4; ++r) pk[r] = (short)f2bf(macc[i][r]);
            *(bf16x4*)&band[rowp][v0] = pk;
          } else if (v0 + 3 >= Aw && v0 <= Bw) {
#pragma unroll
            for (int r = 0; r < 4; ++r) {
              const int v = v0 + r;
              if (v >= Aw && v <= Bw) band[rowp][v] = f2bf(macc[i][r]);
            }
          }
        }
      } else {
        __builtin_amdgcn_s_setprio(0);
      }

      // ---- P-phase: bias from band (wave-private), exp2, write P ----
#pragma unroll
      for (int f = 0; f < 4; ++f) {
        const int sp = (f << 4) + l15;
        const int s = s0 + sp;
#pragma unroll
        for (int j = 0; j < 4; ++j) {
          const int rowp = wr0p + (l4 << 2) + j;
          const int lrow = l0H + rowp;
          const float qa = clipped ? qa_lds[(half << 6) + rowp]
                                   : bf2f(band[rowp][sp + 63 - rowp]);
          float p = exp2f(sc[f][j] + qa);
          p = (s <= lrow) ? p : 0.f;
          denr[j] += p;
          const unsigned short pbf = f2bf(p);
          pb[rowp][sp] = pbf;
          if (!clipped) band[rowp][sp + 63 - rowp] = pbf;
          else pr0r[j] += p;
        }
      }

      // ---- P @ V ----
      __builtin_amdgcn_s_setprio(1);
#pragma unroll
      for (int ks = 0; ks < 2; ++ks) {
        bf16x8 ap = *(const bf16x8*)&pb[wr0p + l15][(ks << 5) + (l4 << 3)];
#pragma unroll
        for (int f = 0; f < 4; ++f) {
          const int d = (f << 4) + l15;
          const int U = ((ks << 2) + l4) ^ ((d >> 3) & 7);
          bf16x8 bv = *(const bf16x8*)&vtb[d][U << 3];
          ov[f] = __builtin_amdgcn_mfma_f32_16x16x32_bf16(ap, bv, ov[f], 0, 0, 0);
        }
      }
      __builtin_amdgcn_s_setprio(0);
    }

    __syncthreads();                 // all waves done with ksb/vtb
    if (c + 1 < nch) WRITEKV();

    // ---- transposed out-band GEMM (wave-private): ow[d][l'] += peW.band ----
    if (active && !clipped) {
      const unsigned short* asrc = bnd ? peB : (peT1 + (s0 - l0H + 448));
      const int astr = bnd ? 128 : 640;
      bf16x8 bb[4];
#pragma unroll
      for (int k2 = 0; k2 < 4; ++k2)
        bb[k2] = *(const bf16x8*)&band[wr0p + l15][(k2 << 5) + (l4 << 3)];
      __builtin_amdgcn_s_setprio(1);
#pragma unroll
      for (int fd = 0; fd < 4; ++fd)
#pragma unroll
        for (int k2 = 0; k2 < 4; ++k2) {
          bf16x8 af = *(const bf16x8*)(asrc + (size_t)((fd << 4) + l15) * astr + (k2 << 5) + (l4 << 3));
          ow[fd] = __builtin_amdgcn_mfma_f32_16x16x32_bf16(af, bb[k2], ow[fd], 0, 0, 0);
        }
      __builtin_amdgcn_s_setprio(0);
    }
    __syncthreads();                 // staged K/V visible; band free next chunk
  }

  // ---- reduce den / pr0 over the 16 lanes sharing each row ----
#pragma unroll
  for (int j = 0; j < 4; ++j) {
#pragma unroll
    for (int m = 1; m < 16; m <<= 1) {
      denr[j] += __shfl_xor(denr[j], m, 64);
      pr0r[j] += __shfl_xor(pr0r[j], m, 64);
    }
  }
  // clipped-region contribution: pr0 * pe[0][d]
#pragma unroll
  for (int f = 0; f < 4; ++f) {
    const float pe0 = pe[(f << 4) + l15];
#pragma unroll
    for (int j = 0; j < 4; ++j) ov[f][j] += pr0r[j] * pe0;
  }

  // ---- transpose ow within the wave's private band region ----
  float (*tbw)[17] = (float(*)[17])&band2[half][wr0p][0];   // 16*136*2B = [64][17] f32
#pragma unroll
  for (int fd = 0; fd < 4; ++fd)
#pragma unroll
    for (int r = 0; r < 4; ++r)
      tbw[(fd << 4) + (l4 << 2) + r][l15] = ow[fd][r];

  // ---- normalize + store bf16 ----
#pragma unroll
  for (int j = 0; j < 4; ++j) {
    const float inv = 1.f / denr[j];
    unsigned short* dst = Oa + (size_t)(b * 1024 + l0 + (wid << 4) + (l4 << 2) + j) * 512 + h * 64;
#pragma unroll
    for (int f = 0; f < 4; ++f) {
      const float o2 = tbw[(f << 4) + l15][(l4 << 2) + j];
      dst[(f << 4) + l15] = f2bf((ov[f][j] + o2) * inv);
    }
  }
}

// ---------------------------------------------------------------------------
extern "C" void kernel_launch(void* const* d_in, const int* in_sizes, int n_in,
                              void* d_out, int out_size, void* d_ws, size_t ws_size,
                              hipStream_t stream) {
  const float* query = (const float*)d_in[0];
  const float* key   = (const float*)d_in[1];
  const float* value = (const float*)d_in[2];
  // d_in[3] attention_mask == 1 -> causal
  const float* Wq = (const float*)d_in[4];
  const float* bq = (const float*)d_in[5];
  const float* Wk = (const float*)d_in[6];
  const float* bk = (const float*)d_in[7];
  const float* Wv = (const float*)d_in[8];
  const float* bv = (const float*)d_in[9];
  const float* pe = (const float*)d_in[10];
  const float* Wo = (const float*)d_in[11];
  const float* bo = (const float*)d_in[12];

  char* ws = (char*)d_ws;
  const size_t SZ_QKV = (size_t)8192 * 512 * 2;           // 8,388,608
  unsigned short* qbuf = (unsigned short*)(ws);
  unsigned short* kbuf = (unsigned short*)(ws + SZ_QKV);
  unsigned short* vbuf = (unsigned short*)(ws + 2 * SZ_QKV);
  unsigned short* obuf = (unsigned short*)(ws + 3 * SZ_QKV);
  char* wbase = ws + 4 * SZ_QKV;
  unsigned short* Wqb  = (unsigned short*)(wbase);
  unsigned short* Wkb  = (unsigned short*)(wbase + 524288);
  unsigned short* Wvb  = (unsigned short*)(wbase + 2 * 524288);
  unsigned short* Wob  = (unsigned short*)(wbase + 3 * 524288);
  unsigned short* pe_b = (unsigned short*)(wbase + 4 * 524288);
  unsigned short* peT1 = (unsigned short*)(wbase + 4 * 524288 + 77824);
  unsigned short* peB  = (unsigned short*)(wbase + 4 * 524288 + 77824 + 81920);
  unsigned short* peBb = (unsigned short*)(wbase + 4 * 524288 + 77824 + 81920 + 16384);
  if (ws_size < (size_t)4 * SZ_QKV + 4 * 524288 + 77824 + 81920 + 16384 + 16384)
    return;

  cvt_w<<<256, 256, 0, stream>>>(Wq, Wqb, 65536);
  cvt_w<<<256, 256, 0, stream>>>(Wk, Wkb, 65536);
  cvt_w<<<256, 256, 0, stream>>>(Wv, Wvb, 65536);
  cvt_w<<<256, 256, 0, stream>>>(Wo, Wob, 65536);
  pe_prep<<<160, 256, 0, stream>>>(pe, pe_b, peT1, peB, peBb);

  {
    GemmArgs ga;
    ga.X[0] = query; ga.X[1] = key; ga.X[2] = value;
    ga.W[0] = Wqb;   ga.W[1] = Wkb; ga.W[2] = Wvb;
    ga.bias[0] = bq; ga.bias[1] = bk; ga.bias[2] = bv;
    ga.scale[0] = ALPHA_Q; ga.scale[1] = 1.f; ga.scale[2] = 1.f;
    ga.Yb[0] = qbuf; ga.Yb[1] = kbuf; ga.Yb[2] = vbuf;
    ga.Yf = nullptr;
    gemm_nt<1><<<dim3(8, 64, 3), 512, 0, stream>>>(ga);
  }

  attn_mfma<<<512, 512, 0, stream>>>(qbuf, kbuf, vbuf, pe_b, peT1, peB, peBb, pe, obuf);

  {
    GemmArgs ga;
    ga.X[0] = obuf; ga.X[1] = nullptr; ga.X[2] = nullptr;
    ga.W[0] = Wob;  ga.W[1] = nullptr; ga.W[2] = nullptr;
    ga.bias[0] = bo; ga.bias[1] = nullptr; ga.bias[2] = nullptr;
    ga.scale[0] = 1.f; ga.scale[1] = 1.f; ga.scale[2] = 1.f;
    ga.Yb[0] = nullptr; ga.Yb[1] = nullptr; ga.Yb[2] = nullptr;
    ga.Yf = (float*)d_out;
    gemm_nt<0><<<dim3(8, 64, 1), 512, 0, stream>>>(ga);
  }
}